// Round 11
// baseline (233.695 us; speedup 1.0000x reference)
//
#include <hip/hip_runtime.h>
#include <hip/hip_bf16.h>

typedef __attribute__((ext_vector_type(8))) short bf16x8;
typedef __attribute__((ext_vector_type(4))) short bf16x4;
typedef __attribute__((ext_vector_type(4))) float f32x4;
typedef __attribute__((ext_vector_type(4))) float f4v;
typedef __attribute__((ext_vector_type(4))) short s4v;

__device__ __forceinline__ short f2bf(float f) {
    union { __hip_bfloat16 h; short s; } u;
    u.h = __float2bfloat16(f);
    return u.s;
}

__device__ __forceinline__ void gload_lds16(const void* g, void* l) {
    __builtin_amdgcn_global_load_lds(
        (const __attribute__((address_space(1))) void*)g,
        (__attribute__((address_space(3))) void*)l,
        16, 0, 0);
}

#define MFMA16(a, b, c) __builtin_amdgcn_mfma_f32_16x16x32_bf16((a), (b), (c), 0, 0, 0)
#define MFMA16K16(a, b, c) __builtin_amdgcn_mfma_f32_16x16x16bf16_1k((a), (b), (c), 0, 0, 0)

// ---------------- fused prep: 3x f32->bf16 cvt + per-batch scale ----------------
__global__ void prep_kernel(const float* __restrict__ x,
                            const float* __restrict__ qw,
                            const float* __restrict__ ow,
                            const float* __restrict__ pd,
                            const float* __restrict__ alphap,
                            s4v* __restrict__ xb, s4v* __restrict__ qb,
                            s4v* __restrict__ ob, float* __restrict__ scales) {
    __shared__ float wsum[4];
    if (blockIdx.x >= 2048) {
        int b = blockIdx.x - 2048;
        float s = 0.f;
        for (int i = threadIdx.x; i < 2048; i += 256) s += pd[b * 2048 + i];
        for (int o = 32; o; o >>= 1) s += __shfl_down(s, o);
        if ((threadIdx.x & 63) == 0) wsum[threadIdx.x >> 6] = s;
        __syncthreads();
        if (threadIdx.x == 0) {
            float t = wsum[0] + wsum[1] + wsum[2] + wsum[3];
            float mean = t * (1.0f / 2048.0f);
            float temp = fmaxf(1.0f + alphap[0] * mean, 1e-6f);
            scales[b] = 0.125f * temp;
        }
        return;
    }
    #pragma unroll
    for (int j = 0; j < 4; ++j) {
        int idx = blockIdx.x * 1024 + j * 256 + threadIdx.x;
        const f4v* src;
        s4v* dst;
        int off;
        if (idx < 1048576)      { src = (const f4v*)x;  dst = xb; off = idx; }
        else if (idx < 1835008) { src = (const f4v*)qw; dst = qb; off = idx - 1048576; }
        else                    { src = (const f4v*)ow; dst = ob; off = idx - 1835008; }
        f4v v = src[off];
        s4v o;
        #pragma unroll
        for (int k = 0; k < 4; ++k) o[k] = f2bf(v[k]);
        dst[off] = o;
    }
}

// ---------------- NT GEMM: C[M,N] = A[M,K] * B[N,K]^T + bias ----------------
template<int BF16_OUT, int NF>
__global__ __launch_bounds__(256, 2)
void gemm_nt(const __hip_bfloat16* __restrict__ A,
             const __hip_bfloat16* __restrict__ Bw,
             const float* __restrict__ bias,
             void* __restrict__ Cv,
             int M, int N, int K) {
    __shared__ short sA[128 * 64];
    __shared__ short sB[NF * 32 * 64];
    const int tid = threadIdx.x;
    const int wave = tid >> 6, lane = tid & 63;
    const int g = lane >> 4, c = lane & 15;
    const int wr = wave >> 1, wc = wave & 1;
    const long m0 = (long)blockIdx.y * 128, n0 = (long)blockIdx.x * (NF * 32);

    f32x4 acc[4][NF];
    #pragma unroll
    for (int m = 0; m < 4; ++m)
        #pragma unroll
        for (int n = 0; n < NF; ++n) acc[m][n] = f32x4{0.f, 0.f, 0.f, 0.f};

    for (int k0 = 0; k0 < K; k0 += 64) {
        #pragma unroll
        for (int i = 0; i < 4; ++i) {
            int cb = (i * 4 + wave) * 64;
            int chunk = cb + lane;
            int row = chunk >> 3;
            int sc = ((chunk & 7) * 16) ^ ((row & 7) << 4);
            const char* gA = (const char*)(A + (m0 + row) * (long)K + k0) + sc;
            gload_lds16(gA, (char*)sA + cb * 16);
        }
        #pragma unroll
        for (int i = 0; i < NF; ++i) {
            int cb = (i * 4 + wave) * 64;
            int chunk = cb + lane;
            int row = chunk >> 3;
            int sc = ((chunk & 7) * 16) ^ ((row & 7) << 4);
            const char* gB = (const char*)(Bw + (n0 + row) * (long)K + k0) + sc;
            gload_lds16(gB, (char*)sB + cb * 16);
        }
        __syncthreads();
        #pragma unroll
        for (int s = 0; s < 2; ++s) {
            bf16x8 af[4], bfr[NF];
            #pragma unroll
            for (int m = 0; m < 4; ++m) {
                int row = wr * 64 + m * 16 + c;
                int kb = (s * 64 + g * 16) ^ ((row & 7) << 4);
                af[m] = *(const bf16x8*)((const char*)sA + row * 128 + kb);
            }
            #pragma unroll
            for (int n = 0; n < NF; ++n) {
                int row = wc * (NF * 16) + n * 16 + c;
                int kb = (s * 64 + g * 16) ^ ((row & 7) << 4);
                bfr[n] = *(const bf16x8*)((const char*)sB + row * 128 + kb);
            }
            #pragma unroll
            for (int m = 0; m < 4; ++m)
                #pragma unroll
                for (int n = 0; n < NF; ++n)
                    acc[m][n] = MFMA16(af[m], bfr[n], acc[m][n]);
        }
        __syncthreads();
    }

    #pragma unroll
    for (int m = 0; m < 4; ++m) {
        #pragma unroll
        for (int n = 0; n < NF; ++n) {
            long col = n0 + wc * (NF * 16) + n * 16 + c;
            float bv = bias[col];
            #pragma unroll
            for (int r = 0; r < 4; ++r) {
                long row = m0 + wr * 64 + m * 16 + g * 4 + r;
                float v = acc[m][n][r] + bv;
                if (BF16_OUT)
                    ((__hip_bfloat16*)Cv)[row * N + col] = __float2bfloat16(v);
                else
                    ((float*)Cv)[row * N + col] = v;
            }
        }
    }
}

// ---------------- attention v11: swapped-QK, in-reg P, float4 alibi ----------
// S^T = mfma(A=K, B=Q): lane (c,g) owns P[kv=nf*16+g*4+r][q=c].
// Alibi: per-lane kv values are CONSECUTIVE & 16B-aligned -> 4 float4 loads
// per iter (full cacheline utilization). PV via mfma_f32_16x16x16 (K=16).
// LDS 34.5 KB + VGPR ~80 -> __launch_bounds__(256,4): 4 blocks/CU.

#define VSTRIDE 74

__global__ __launch_bounds__(256, 4)
void attn_kernel(const __hip_bfloat16* __restrict__ qkv,   // [B*L, 3072]
                 const float* __restrict__ alibi,          // [H, L, L]
                 const float* __restrict__ scales,         // [B]
                 __hip_bfloat16* __restrict__ out) {       // [B*L, 1024]
    __shared__ short sK[2][64 * 64];          // 16 KB, swizzled staging
    __shared__ short sVt[2][64 * VSTRIDE];    // 18.5 KB, [64 d][64 kv + 10 pad]

    const int h = blockIdx.x, b = blockIdx.y;
    const int qt = 31 - blockIdx.z;           // longest q-tiles dispatched first
    const int nIter = qt + 1;
    const int tid = threadIdx.x;
    const int wave = tid >> 6, lane = tid & 63;
    const int g = lane >> 4, c = lane & 15;
    const float scale = scales[b];
    const long base_bl = (long)b * 2048;

    const int q0w = qt * 64 + wave * 16;
    const int q_lane = q0w + c;

    const __hip_bfloat16* qrow = qkv + (base_bl + q_lane) * 3072 + h * 64;
    bf16x8 qf0 = *(const bf16x8*)(qrow + g * 8);
    bf16x8 qf1 = *(const bf16x8*)(qrow + 32 + g * 8);

    const __hip_bfloat16* kg = qkv + base_bl * 3072 + 1024 + h * 64;
    const __hip_bfloat16* vg = qkv + base_bl * 3072 + 2048 + h * 64;
    // per-lane alibi row = q_lane; lane's 4 kv values start at col nf*16 + g*4
    const float* ab_base = alibi + (long)h * 2048 * 2048 + (long)q_lane * 2048 + g * 4;

    const int p2 = tid & 31;
    const int d0 = (tid >> 5) * 8;
    const __hip_bfloat16* vrow = vg + (long)(2 * p2) * 3072 + d0;

    f32x4 acc[4];                 // acc[df][r] = O[q=c][d=df*16+g*4+r]
    float accL = 0.f, m = -3e38f;
    #pragma unroll
    for (int d = 0; d < 4; ++d) acc[d] = f32x4{0.f, 0.f, 0.f, 0.f};

    f4v ab[4], abn[4];

    // prologue: stage K(0), V(0), ab(0)
    {
        #pragma unroll
        for (int i = 0; i < 2; ++i) {
            int cb = (i * 4 + wave) * 64;
            int chunk = cb + lane;
            int row = chunk >> 3;
            int sc = ((chunk & 7) * 16) ^ ((row & 7) << 4);
            gload_lds16((const char*)(kg + (long)row * 3072) + sc,
                        (char*)sK[0] + cb * 16);
        }
        bf16x8 va = *(const bf16x8*)vrow;
        bf16x8 vb = *(const bf16x8*)(vrow + 3072);
        #pragma unroll
        for (int j = 0; j < 8; ++j) {
            unsigned pk = ((unsigned)(unsigned short)va[j]) |
                          (((unsigned)(unsigned short)vb[j]) << 16);
            *(unsigned*)((char*)sVt[0] + (d0 + j) * (VSTRIDE * 2) + p2 * 4) = pk;
        }
        #pragma unroll
        for (int nf = 0; nf < 4; ++nf) {
            ab[nf] = *(const f4v*)(ab_base + nf * 16);
            abn[nf] = f4v{0.f, 0.f, 0.f, 0.f};
        }
    }
    __syncthreads();

    for (int t = 0; t < nIter; ++t) {
        const int cur = t & 1;
        const int kv0 = t * 64;
        bf16x8 va, vb;
        const bool haveNext = (t + 1 < nIter);
        if (haveNext) {
            #pragma unroll
            for (int i = 0; i < 2; ++i) {
                int cb = (i * 4 + wave) * 64;
                int chunk = cb + lane;
                int row = chunk >> 3;
                int sc = ((chunk & 7) * 16) ^ ((row & 7) << 4);
                gload_lds16((const char*)(kg + (long)(kv0 + 64 + row) * 3072) + sc,
                            (char*)sK[cur ^ 1] + cb * 16);
            }
            const __hip_bfloat16* vp = vrow + (long)(kv0 + 64) * 3072;
            va = *(const bf16x8*)vp;
            vb = *(const bf16x8*)(vp + 3072);
            #pragma unroll
            for (int nf = 0; nf < 4; ++nf)
                abn[nf] = *(const f4v*)(ab_base + kv0 + 64 + nf * 16);
        }

        // ---- compute tile (swapped QK, in-register P) ----
        {
            const short* sKc = sK[cur];
            const short* sVtc = sVt[cur];
            const bool diag = (t == qt);
            f32x4 accs[4];
            const int swz = (c & 7) << 4;
            __builtin_amdgcn_s_setprio(1);
            #pragma unroll
            for (int nf = 0; nf < 4; ++nf) {
                const char* kb = (const char*)sKc + (nf * 16 + c) * 128;
                bf16x8 kf0 = *(const bf16x8*)(kb + ((g * 16) ^ swz));
                bf16x8 kf1 = *(const bf16x8*)(kb + ((64 + g * 16) ^ swz));
                accs[nf] = f32x4{0.f, 0.f, 0.f, 0.f};
                accs[nf] = MFMA16(kf0, qf0, accs[nf]);   // swapped operands
                accs[nf] = MFMA16(kf1, qf1, accs[nf]);
            }
            __builtin_amdgcn_s_setprio(0);

            float s[4][4];
            float pmax = -3e38f;
            #pragma unroll
            for (int nf = 0; nf < 4; ++nf)
                #pragma unroll
                for (int r = 0; r < 4; ++r) {
                    float sv = fmaf(accs[nf][r], scale, ab[nf][r]);
                    if (diag && (kv0 + nf * 16 + g * 4 + r > q_lane)) sv = -1e30f;
                    s[nf][r] = sv;
                    pmax = fmaxf(pmax, sv);
                }
            bool ok = (pmax <= m + 8.0f);
            if (!__all(ok)) {
                float mx = fmaxf(pmax, __shfl_xor(pmax, 16));
                mx = fmaxf(mx, __shfl_xor(mx, 32));
                float mn = fmaxf(m, mx);
                float alpha = __expf(m - mn);
                m = mn;
                accL *= alpha;
                #pragma unroll
                for (int d = 0; d < 4; ++d)
                    #pragma unroll
                    for (int r = 0; r < 4; ++r) acc[d][r] *= alpha;
            }
            unsigned pw[4][2];
            float ls = 0.f;
            #pragma unroll
            for (int nf = 0; nf < 4; ++nf) {
                float e0 = __expf(s[nf][0] - m);
                float e1 = __expf(s[nf][1] - m);
                float e2 = __expf(s[nf][2] - m);
                float e3 = __expf(s[nf][3] - m);
                ls += (e0 + e1) + (e2 + e3);
                pw[nf][0] = ((unsigned)(unsigned short)f2bf(e0)) |
                            (((unsigned)(unsigned short)f2bf(e1)) << 16);
                pw[nf][1] = ((unsigned)(unsigned short)f2bf(e2)) |
                            (((unsigned)(unsigned short)f2bf(e3)) << 16);
            }
            ls += __shfl_xor(ls, 16);
            ls += __shfl_xor(ls, 32);
            accL += ls;

            __builtin_amdgcn_s_setprio(1);
            #pragma unroll
            for (int df = 0; df < 4; ++df) {
                const char* vb2 = (const char*)sVtc + (df * 16 + c) * (VSTRIDE * 2);
                #pragma unroll
                for (int nf = 0; nf < 4; ++nf) {
                    bf16x4 vf = *(const bf16x4*)(vb2 + (nf * 16 + g * 4) * 2);
                    union { unsigned w[2]; bf16x4 v; } pu;
                    pu.w[0] = pw[nf][0];
                    pu.w[1] = pw[nf][1];
                    acc[df] = MFMA16K16(vf, pu.v, acc[df]);
                }
            }
            __builtin_amdgcn_s_setprio(0);
        }

        if (haveNext) {
            #pragma unroll
            for (int j = 0; j < 8; ++j) {
                unsigned pk = ((unsigned)(unsigned short)va[j]) |
                              (((unsigned)(unsigned short)vb[j]) << 16);
                *(unsigned*)((char*)sVt[cur ^ 1] + (d0 + j) * (VSTRIDE * 2) + p2 * 4) = pk;
            }
        }
        __syncthreads();
        #pragma unroll
        for (int nf = 0; nf < 4; ++nf)
            ab[nf] = abn[nf];
    }

    // epilogue: O[q=c][d=df*16+g*4+r], packed 8B stores
    __hip_bfloat16* op = out + (base_bl + q_lane) * 1024 + h * 64;
    float inv = 1.0f / accL;
    #pragma unroll
    for (int df = 0; df < 4; ++df) {
        s4v o;
        #pragma unroll
        for (int r = 0; r < 4; ++r) o[r] = f2bf(acc[df][r] * inv);
        *(s4v*)(op + df * 16 + g * 4) = o;
    }
}

extern "C" void kernel_launch(void* const* d_in, const int* in_sizes, int n_in,
                              void* d_out, int out_size, void* d_ws, size_t ws_size,
                              hipStream_t stream) {
    const float* x      = (const float*)d_in[0];
    const float* phylo  = (const float*)d_in[1];
    const float* alibi  = (const float*)d_in[2];
    const float* qkv_w  = (const float*)d_in[4];
    const float* qkv_b  = (const float*)d_in[5];
    const float* out_w  = (const float*)d_in[6];
    const float* out_b  = (const float*)d_in[7];
    const float* alphap = (const float*)d_in[8];

    char* ws = (char*)d_ws;
    __hip_bfloat16* xbf   = (__hip_bfloat16*)(ws);                 // 8 MB
    __hip_bfloat16* qwbf  = (__hip_bfloat16*)(ws + (8l << 20));    // 6 MB
    __hip_bfloat16* owbf  = (__hip_bfloat16*)(ws + (14l << 20));   // 2 MB
    __hip_bfloat16* qkvbf = (__hip_bfloat16*)(ws + (16l << 20));   // 24 MB
    __hip_bfloat16* aobf  = (__hip_bfloat16*)(ws + (40l << 20));   // 8 MB
    float* scales         = (float*)(ws + (48l << 20));            // 2 floats

    prep_kernel<<<2050, 256, 0, stream>>>(x, qkv_w, out_w, phylo, alphap,
                                          (s4v*)xbf, (s4v*)qwbf, (s4v*)owbf, scales);

    gemm_nt<1, 4><<<dim3(24, 32), 256, 0, stream>>>(xbf, qwbf, qkv_b, qkvbf,
                                                    4096, 3072, 1024);
    attn_kernel<<<dim3(16, 2, 32), 256, 0, stream>>>(qkvbf, alibi, scales, aobf);
    gemm_nt<0, 2><<<dim3(16, 32), 256, 0, stream>>>(aobf, owbf, out_b, d_out,
                                                    4096, 1024, 1024);
}

// Round 12
// 136.781 us; speedup vs baseline: 1.7085x; 1.7085x over previous
//
#include <hip/hip_runtime.h>
#include <hip/hip_bf16.h>

typedef __attribute__((ext_vector_type(8))) short bf16x8;
typedef __attribute__((ext_vector_type(4))) float f32x4;
typedef __attribute__((ext_vector_type(4))) float f4v;
typedef __attribute__((ext_vector_type(4))) short s4v;

__device__ __forceinline__ short f2bf(float f) {
    union { __hip_bfloat16 h; short s; } u;
    u.h = __float2bfloat16(f);
    return u.s;
}

__device__ __forceinline__ float bf2f(short s) {
    union { short s; __hip_bfloat16 h; } u;
    u.s = s;
    return __bfloat162float(u.h);
}

__device__ __forceinline__ void gload_lds16(const void* g, void* l) {
    __builtin_amdgcn_global_load_lds(
        (const __attribute__((address_space(1))) void*)g,
        (__attribute__((address_space(3))) void*)l,
        16, 0, 0);
}

#define MFMA16(a, b, c) __builtin_amdgcn_mfma_f32_16x16x32_bf16((a), (b), (c), 0, 0, 0)

// ---------------- fused prep: 3x f32->bf16 cvt + per-batch scale ----------------
__global__ void prep_kernel(const float* __restrict__ x,
                            const float* __restrict__ qw,
                            const float* __restrict__ ow,
                            const float* __restrict__ pd,
                            const float* __restrict__ alphap,
                            s4v* __restrict__ xb, s4v* __restrict__ qb,
                            s4v* __restrict__ ob, float* __restrict__ scales) {
    __shared__ float wsum[4];
    if (blockIdx.x >= 2048) {
        int b = blockIdx.x - 2048;
        float s = 0.f;
        for (int i = threadIdx.x; i < 2048; i += 256) s += pd[b * 2048 + i];
        for (int o = 32; o; o >>= 1) s += __shfl_down(s, o);
        if ((threadIdx.x & 63) == 0) wsum[threadIdx.x >> 6] = s;
        __syncthreads();
        if (threadIdx.x == 0) {
            float t = wsum[0] + wsum[1] + wsum[2] + wsum[3];
            float mean = t * (1.0f / 2048.0f);
            float temp = fmaxf(1.0f + alphap[0] * mean, 1e-6f);
            scales[b] = 0.125f * temp;
        }
        return;
    }
    #pragma unroll
    for (int j = 0; j < 4; ++j) {
        int idx = blockIdx.x * 1024 + j * 256 + threadIdx.x;
        const f4v* src;
        s4v* dst;
        int off;
        if (idx < 1048576)      { src = (const f4v*)x;  dst = xb; off = idx; }
        else if (idx < 1835008) { src = (const f4v*)qw; dst = qb; off = idx - 1048576; }
        else                    { src = (const f4v*)ow; dst = ob; off = idx - 1835008; }
        f4v v = src[off];
        s4v o;
        #pragma unroll
        for (int k = 0; k < 4; ++k) o[k] = f2bf(v[k]);
        dst[off] = o;
    }
}

// ---------------- NT GEMM: C[M,N] = A[M,K] * B[N,K]^T + bias ----------------
template<int BF16_OUT, int NF>
__global__ __launch_bounds__(256, 2)
void gemm_nt(const __hip_bfloat16* __restrict__ A,
             const __hip_bfloat16* __restrict__ Bw,
             const float* __restrict__ bias,
             void* __restrict__ Cv,
             int M, int N, int K) {
    __shared__ short sA[128 * 64];
    __shared__ short sB[NF * 32 * 64];
    const int tid = threadIdx.x;
    const int wave = tid >> 6, lane = tid & 63;
    const int g = lane >> 4, c = lane & 15;
    const int wr = wave >> 1, wc = wave & 1;
    const long m0 = (long)blockIdx.y * 128, n0 = (long)blockIdx.x * (NF * 32);

    f32x4 acc[4][NF];
    #pragma unroll
    for (int m = 0; m < 4; ++m)
        #pragma unroll
        for (int n = 0; n < NF; ++n) acc[m][n] = f32x4{0.f, 0.f, 0.f, 0.f};

    for (int k0 = 0; k0 < K; k0 += 64) {
        #pragma unroll
        for (int i = 0; i < 4; ++i) {
            int cb = (i * 4 + wave) * 64;
            int chunk = cb + lane;
            int row = chunk >> 3;
            int sc = ((chunk & 7) * 16) ^ ((row & 7) << 4);
            const char* gA = (const char*)(A + (m0 + row) * (long)K + k0) + sc;
            gload_lds16(gA, (char*)sA + cb * 16);
        }
        #pragma unroll
        for (int i = 0; i < NF; ++i) {
            int cb = (i * 4 + wave) * 64;
            int chunk = cb + lane;
            int row = chunk >> 3;
            int sc = ((chunk & 7) * 16) ^ ((row & 7) << 4);
            const char* gB = (const char*)(Bw + (n0 + row) * (long)K + k0) + sc;
            gload_lds16(gB, (char*)sB + cb * 16);
        }
        __syncthreads();
        #pragma unroll
        for (int s = 0; s < 2; ++s) {
            bf16x8 af[4], bfr[NF];
            #pragma unroll
            for (int m = 0; m < 4; ++m) {
                int row = wr * 64 + m * 16 + c;
                int kb = (s * 64 + g * 16) ^ ((row & 7) << 4);
                af[m] = *(const bf16x8*)((const char*)sA + row * 128 + kb);
            }
            #pragma unroll
            for (int n = 0; n < NF; ++n) {
                int row = wc * (NF * 16) + n * 16 + c;
                int kb = (s * 64 + g * 16) ^ ((row & 7) << 4);
                bfr[n] = *(const bf16x8*)((const char*)sB + row * 128 + kb);
            }
            #pragma unroll
            for (int m = 0; m < 4; ++m)
                #pragma unroll
                for (int n = 0; n < NF; ++n)
                    acc[m][n] = MFMA16(af[m], bfr[n], acc[m][n]);
        }
        __syncthreads();
    }

    #pragma unroll
    for (int m = 0; m < 4; ++m) {
        #pragma unroll
        for (int n = 0; n < NF; ++n) {
            long col = n0 + wc * (NF * 16) + n * 16 + c;
            float bv = bias[col];
            #pragma unroll
            for (int r = 0; r < 4; ++r) {
                long row = m0 + wr * 64 + m * 16 + g * 4 + r;
                float v = acc[m][n][r] + bv;
                if (BF16_OUT)
                    ((__hip_bfloat16*)Cv)[row * N + col] = __float2bfloat16(v);
                else
                    ((float*)Cv)[row * N + col] = v;
            }
        }
    }
}

// ---------------- attention v12: R8 body + kv-split for qt>=16 --------------
// z < 32: qt = 31-(z>>1), split = z&1 (half kv-range each; split1 owns diag).
// z >= 32: qt = 47-z, full range. Splits write locally-normalized bf16
// partials + per-row (m,l); merge_kernel combines via LSE weights.

__device__ __forceinline__ void compute_tile(
    const short* sKc, const short* sVtc, short* sPw,
    bf16x8 qf0, bf16x8 qf1,
    f32x4 (&acc_o)[4], f32x4& accL, float (&m)[4],
    const float (&ab)[4][4],
    float scale, int qi0, int kv0, bool diag, int g, int c)
{
    f32x4 accs[4];
    const int swz = (c & 7) << 4;
    __builtin_amdgcn_s_setprio(1);
    #pragma unroll
    for (int nf = 0; nf < 4; ++nf) {
        const char* kb = (const char*)sKc + (nf * 16 + c) * 128;
        bf16x8 kf0 = *(const bf16x8*)(kb + ((g * 16) ^ swz));
        bf16x8 kf1 = *(const bf16x8*)(kb + ((64 + g * 16) ^ swz));
        accs[nf] = f32x4{0.f, 0.f, 0.f, 0.f};
        accs[nf] = MFMA16(qf0, kf0, accs[nf]);
        accs[nf] = MFMA16(qf1, kf1, accs[nf]);
    }
    __builtin_amdgcn_s_setprio(0);
    float s[4][4], pmax[4];
    bool ok = true;
    #pragma unroll
    for (int r = 0; r < 4; ++r) {
        int qi = qi0 + r;
        #pragma unroll
        for (int nf = 0; nf < 4; ++nf) {
            float sv = fmaf(accs[nf][r], scale, ab[nf][r]);
            if (diag && (kv0 + nf * 16 + c > qi)) sv = -1e30f;
            s[r][nf] = sv;
        }
        pmax[r] = fmaxf(fmaxf(s[r][0], s[r][1]), fmaxf(s[r][2], s[r][3]));
        ok = ok && (pmax[r] <= m[r] + 8.0f);
    }
    if (!__all(ok)) {   // rare after first tile
        #pragma unroll
        for (int r = 0; r < 4; ++r) {
            float mx = pmax[r];
            mx = fmaxf(mx, __shfl_xor(mx, 1));
            mx = fmaxf(mx, __shfl_xor(mx, 2));
            mx = fmaxf(mx, __shfl_xor(mx, 4));
            mx = fmaxf(mx, __shfl_xor(mx, 8));
            float mn = fmaxf(m[r], mx);
            float alpha = __expf(m[r] - mn);
            m[r] = mn;
            accL[r] *= alpha;
            #pragma unroll
            for (int d = 0; d < 4; ++d) acc_o[d][r] *= alpha;
        }
    }
    #pragma unroll
    for (int r = 0; r < 4; ++r)
        #pragma unroll
        for (int nf = 0; nf < 4; ++nf)
            sPw[(g * 4 + r) * 72 + nf * 16 + c] = f2bf(__expf(s[r][nf] - m[r]));
    asm volatile("s_waitcnt lgkmcnt(0)" ::: "memory");
    bf16x8 pf0 = *(const bf16x8*)((const char*)sPw + c * 144 + g * 16);
    bf16x8 pf1 = *(const bf16x8*)((const char*)sPw + c * 144 + 64 + g * 16);
    const short ONE = 0x3F80;
    const bf16x8 ones = {ONE, ONE, ONE, ONE, ONE, ONE, ONE, ONE};
    __builtin_amdgcn_s_setprio(1);
    accL = MFMA16(pf0, ones, accL);
    accL = MFMA16(pf1, ones, accL);
    #pragma unroll
    for (int d = 0; d < 4; ++d) {
        const char* vb = (const char*)sVtc + (d * 16 + c) * 144;
        bf16x8 vf0 = *(const bf16x8*)(vb + g * 16);
        bf16x8 vf1 = *(const bf16x8*)(vb + 64 + g * 16);
        acc_o[d] = MFMA16(pf0, vf0, acc_o[d]);
        acc_o[d] = MFMA16(pf1, vf1, acc_o[d]);
    }
    __builtin_amdgcn_s_setprio(0);
}

__global__ __launch_bounds__(256, 3)
void attn_kernel(const __hip_bfloat16* __restrict__ qkv,   // [B*L, 3072]
                 const float* __restrict__ alibi,          // [H, L, L]
                 const float* __restrict__ scales,         // [B]
                 __hip_bfloat16* __restrict__ out,         // [B*L, 1024]
                 __hip_bfloat16* __restrict__ pO,          // partials [.,64,64]
                 float2* __restrict__ pML) {               // per-row (m,l)
    __shared__ short sK[2][64 * 64];      // 16 KB, swizzled staging
    __shared__ short sVt[2][64 * 72];     // 18 KB, [64 d][64 kv + 8 pad]
    __shared__ short sP[4][16 * 72];      // 9 KB, per-wave

    const int h = blockIdx.x, b = blockIdx.y;
    const int z = blockIdx.z;
    int qt, t0, t1, split;
    if (z < 32) {                          // long q-tiles, kv-split in two
        qt = 31 - (z >> 1);
        split = z & 1;
        int nIter = qt + 1;
        int half = nIter >> 1;
        t0 = split ? half : 0;
        t1 = split ? nIter : half;
    } else {                               // short q-tiles, full range
        qt = 47 - z;
        split = -1;
        t0 = 0;
        t1 = qt + 1;
    }
    const int tid = threadIdx.x;
    const int wave = tid >> 6, lane = tid & 63;
    const int g = lane >> 4, c = lane & 15;
    const float scale = scales[b];
    const long base_bl = (long)b * 2048;

    const int q0 = qt * 64 + wave * 16;

    const __hip_bfloat16* qrow = qkv + (base_bl + q0 + c) * 3072 + h * 64;
    bf16x8 qf0 = *(const bf16x8*)(qrow + g * 8);
    bf16x8 qf1 = *(const bf16x8*)(qrow + 32 + g * 8);

    const __hip_bfloat16* kg = qkv + base_bl * 3072 + 1024 + h * 64;
    const __hip_bfloat16* vg = qkv + base_bl * 3072 + 2048 + h * 64;
    const float* ab_base = alibi + (long)h * 2048 * 2048 + (long)(q0 + g * 4) * 2048;

    const int p2 = tid & 31;
    const int d0 = (tid >> 5) * 8;
    const __hip_bfloat16* vrow = vg + (long)(2 * p2) * 3072 + d0;

    f32x4 acc[4], accL;
    float m[4];
    #pragma unroll
    for (int d = 0; d < 4; ++d) acc[d] = f32x4{0.f, 0.f, 0.f, 0.f};
    accL = f32x4{0.f, 0.f, 0.f, 0.f};
    #pragma unroll
    for (int r = 0; r < 4; ++r) m[r] = -3e38f;

    float ab[4][4], abn[4][4];

    // prologue: stage K(t0), V(t0), ab(t0) — note parity buffer t0&1
    {
        const int kvp = t0 * 64;
        #pragma unroll
        for (int i = 0; i < 2; ++i) {
            int cb = (i * 4 + wave) * 64;
            int chunk = cb + lane;
            int row = chunk >> 3;
            int sc = ((chunk & 7) * 16) ^ ((row & 7) << 4);
            gload_lds16((const char*)(kg + (long)(kvp + row) * 3072) + sc,
                        (char*)sK[t0 & 1] + cb * 16);
        }
        const __hip_bfloat16* vp = vrow + (long)kvp * 3072;
        bf16x8 va = *(const bf16x8*)vp;
        bf16x8 vb = *(const bf16x8*)(vp + 3072);
        #pragma unroll
        for (int j = 0; j < 8; ++j) {
            unsigned pk = ((unsigned)(unsigned short)va[j]) |
                          (((unsigned)(unsigned short)vb[j]) << 16);
            *(unsigned*)((char*)sVt[t0 & 1] + (d0 + j) * 144 + p2 * 4) = pk;
        }
        #pragma unroll
        for (int nf = 0; nf < 4; ++nf)
            #pragma unroll
            for (int r = 0; r < 4; ++r) {
                ab[nf][r] = ab_base[(long)r * 2048 + kvp + nf * 16 + c];
                abn[nf][r] = 0.f;
            }
    }
    __syncthreads();

    for (int t = t0; t < t1; ++t) {
        const int cur = t & 1;
        const int kv0 = t * 64;
        bf16x8 va, vb;
        const bool haveNext = (t + 1 < t1);
        if (haveNext) {
            #pragma unroll
            for (int i = 0; i < 2; ++i) {
                int cb = (i * 4 + wave) * 64;
                int chunk = cb + lane;
                int row = chunk >> 3;
                int sc = ((chunk & 7) * 16) ^ ((row & 7) << 4);
                gload_lds16((const char*)(kg + (long)(kv0 + 64 + row) * 3072) + sc,
                            (char*)sK[cur ^ 1] + cb * 16);
            }
            const __hip_bfloat16* vp = vrow + (long)(kv0 + 64) * 3072;
            va = *(const bf16x8*)vp;
            vb = *(const bf16x8*)(vp + 3072);
            #pragma unroll
            for (int nf = 0; nf < 4; ++nf)
                #pragma unroll
                for (int r = 0; r < 4; ++r)
                    abn[nf][r] = ab_base[(long)r * 2048 + kv0 + 64 + nf * 16 + c];
        }

        compute_tile(sK[cur], sVt[cur], &sP[wave][0], qf0, qf1,
                     acc, accL, m, ab, scale, q0 + g * 4, kv0, t == qt, g, c);

        if (haveNext) {
            #pragma unroll
            for (int j = 0; j < 8; ++j) {
                unsigned pk = ((unsigned)(unsigned short)va[j]) |
                              (((unsigned)(unsigned short)vb[j]) << 16);
                *(unsigned*)((char*)sVt[cur ^ 1] + (d0 + j) * 144 + p2 * 4) = pk;
            }
        }
        __syncthreads();
        #pragma unroll
        for (int nf = 0; nf < 4; ++nf)
            #pragma unroll
            for (int r = 0; r < 4; ++r)
                ab[nf][r] = abn[nf][r];
    }

    if (split >= 0) {
        // store locally-normalized partials + (m,l) per row
        const long pbase = ((((long)b * 16 + h) * 16 + (qt - 16)) * 2 + split) * 64;
        #pragma unroll
        for (int r = 0; r < 4; ++r) {
            int ql = wave * 16 + g * 4 + r;
            float invL = 1.0f / accL[r];
            __hip_bfloat16* pp = pO + (pbase + ql) * 64;
            #pragma unroll
            for (int d = 0; d < 4; ++d)
                pp[d * 16 + c] = __float2bfloat16(acc[d][r] * invL);
            if (c == 0) pML[pbase + ql] = float2{m[r], accL[r]};
        }
    } else {
        __hip_bfloat16* op = out + (base_bl + q0 + g * 4) * 1024 + h * 64;
        #pragma unroll
        for (int r = 0; r < 4; ++r) {
            float inv = 1.0f / accL[r];
            #pragma unroll
            for (int d = 0; d < 4; ++d)
                op[(long)r * 1024 + d * 16 + c] = __float2bfloat16(acc[d][r] * inv);
        }
    }
}

// ---------------- LSE merge of the two kv-splits (qt >= 16) ----------------
__global__ void merge_kernel(const __hip_bfloat16* __restrict__ pO,
                             const float2* __restrict__ pML,
                             __hip_bfloat16* __restrict__ out) {
    const int qt = 16 + blockIdx.x;
    const int h = blockIdx.y, b = blockIdx.z;
    const int t = threadIdx.x;
    const int row = t >> 2;
    const int c0 = (t & 3) << 4;
    const long base = (((long)b * 16 + h) * 16 + blockIdx.x) * 2;
    float2 ml1 = pML[(base + 0) * 64 + row];
    float2 ml2 = pML[(base + 1) * 64 + row];
    float M = fmaxf(ml1.x, ml2.x);
    float w1 = __expf(ml1.x - M) * ml1.y;
    float w2 = __expf(ml2.x - M) * ml2.y;
    float inv = 1.0f / (w1 + w2);
    w1 *= inv;
    w2 *= inv;
    const bf16x8* p1 = (const bf16x8*)(pO + ((base + 0) * 64 + row) * 64 + c0);
    const bf16x8* p2 = (const bf16x8*)(pO + ((base + 1) * 64 + row) * 64 + c0);
    __hip_bfloat16* op = out + ((long)b * 2048 + (long)qt * 64 + row) * 1024 + h * 64 + c0;
    #pragma unroll
    for (int k = 0; k < 2; ++k) {
        bf16x8 a = p1[k], bv = p2[k];
        bf16x8 o;
        #pragma unroll
        for (int j = 0; j < 8; ++j)
            o[j] = f2bf(bf2f(a[j]) * w1 + bf2f(bv[j]) * w2);
        *(bf16x8*)(op + k * 8) = o;
    }
}

extern "C" void kernel_launch(void* const* d_in, const int* in_sizes, int n_in,
                              void* d_out, int out_size, void* d_ws, size_t ws_size,
                              hipStream_t stream) {
    const float* x      = (const float*)d_in[0];
    const float* phylo  = (const float*)d_in[1];
    const float* alibi  = (const float*)d_in[2];
    const float* qkv_w  = (const float*)d_in[4];
    const float* qkv_b  = (const float*)d_in[5];
    const float* out_w  = (const float*)d_in[6];
    const float* out_b  = (const float*)d_in[7];
    const float* alphap = (const float*)d_in[8];

    char* ws = (char*)d_ws;
    __hip_bfloat16* xbf   = (__hip_bfloat16*)(ws);                 // 8 MB (dead after qkv GEMM)
    __hip_bfloat16* qwbf  = (__hip_bfloat16*)(ws + (8l << 20));    // 6 MB (dead after qkv GEMM)
    __hip_bfloat16* owbf  = (__hip_bfloat16*)(ws + (14l << 20));   // 2 MB (live till out GEMM)
    __hip_bfloat16* qkvbf = (__hip_bfloat16*)(ws + (16l << 20));   // 24 MB
    __hip_bfloat16* aobf  = (__hip_bfloat16*)(ws + (40l << 20));   // 8 MB
    float* scales         = (float*)(ws + (48l << 20));            // 2 floats
    // attn partials overlap the DEAD xbf region (attn runs after qkv GEMM):
    __hip_bfloat16* pO    = (__hip_bfloat16*)(ws);                 // 8 MB
    float2* pML           = (float2*)(ws + (8l << 20));            // 0.5 MB (in dead qwbf)

    prep_kernel<<<2050, 256, 0, stream>>>(x, qkv_w, out_w, phylo, alphap,
                                          (s4v*)xbf, (s4v*)qwbf, (s4v*)owbf, scales);

    gemm_nt<1, 4><<<dim3(24, 32), 256, 0, stream>>>(xbf, qwbf, qkv_b, qkvbf,
                                                    4096, 3072, 1024);
    attn_kernel<<<dim3(16, 2, 48), 256, 0, stream>>>(qkvbf, alibi, scales, aobf,
                                                     pO, pML);
    merge_kernel<<<dim3(16, 16, 2), 256, 0, stream>>>(pO, pML, aobf);
    gemm_nt<0, 2><<<dim3(16, 32), 256, 0, stream>>>(aobf, owbf, out_b, d_out,
                                                    4096, 1024, 1024);
}

// Round 13
// 129.756 us; speedup vs baseline: 1.8010x; 1.0541x over previous
//
#include <hip/hip_runtime.h>
#include <hip/hip_bf16.h>

typedef __attribute__((ext_vector_type(8))) short bf16x8;
typedef __attribute__((ext_vector_type(4))) float f32x4;
typedef __attribute__((ext_vector_type(4))) float f4v;
typedef __attribute__((ext_vector_type(4))) short s4v;

__device__ __forceinline__ short f2bf(float f) {
    union { __hip_bfloat16 h; short s; } u;
    u.h = __float2bfloat16(f);
    return u.s;
}

__device__ __forceinline__ void gload_lds16(const void* g, void* l) {
    __builtin_amdgcn_global_load_lds(
        (const __attribute__((address_space(1))) void*)g,
        (__attribute__((address_space(3))) void*)l,
        16, 0, 0);
}

#define MFMA16(a, b, c) __builtin_amdgcn_mfma_f32_16x16x32_bf16((a), (b), (c), 0, 0, 0)

// ---------------- fused prep: 3x f32->bf16 cvt + per-batch scale ----------------
__global__ void prep_kernel(const float* __restrict__ x,
                            const float* __restrict__ qw,
                            const float* __restrict__ ow,
                            const float* __restrict__ pd,
                            const float* __restrict__ alphap,
                            s4v* __restrict__ xb, s4v* __restrict__ qb,
                            s4v* __restrict__ ob, float* __restrict__ scales) {
    __shared__ float wsum[4];
    if (blockIdx.x >= 2048) {
        int b = blockIdx.x - 2048;
        float s = 0.f;
        for (int i = threadIdx.x; i < 2048; i += 256) s += pd[b * 2048 + i];
        for (int o = 32; o; o >>= 1) s += __shfl_down(s, o);
        if ((threadIdx.x & 63) == 0) wsum[threadIdx.x >> 6] = s;
        __syncthreads();
        if (threadIdx.x == 0) {
            float t = wsum[0] + wsum[1] + wsum[2] + wsum[3];
            float mean = t * (1.0f / 2048.0f);
            float temp = fmaxf(1.0f + alphap[0] * mean, 1e-6f);
            scales[b] = 0.125f * temp;
        }
        return;
    }
    #pragma unroll
    for (int j = 0; j < 4; ++j) {
        int idx = blockIdx.x * 1024 + j * 256 + threadIdx.x;
        const f4v* src;
        s4v* dst;
        int off;
        if (idx < 1048576)      { src = (const f4v*)x;  dst = xb; off = idx; }
        else if (idx < 1835008) { src = (const f4v*)qw; dst = qb; off = idx - 1048576; }
        else                    { src = (const f4v*)ow; dst = ob; off = idx - 1835008; }
        f4v v = src[off];
        s4v o;
        #pragma unroll
        for (int k = 0; k < 4; ++k) o[k] = f2bf(v[k]);
        dst[off] = o;
    }
}

// ---------------- NT GEMM: C[M,N] = A[M,K] * B[N,K]^T + bias ----------------
template<int BF16_OUT, int NF>
__global__ __launch_bounds__(256, 2)
void gemm_nt(const __hip_bfloat16* __restrict__ A,
             const __hip_bfloat16* __restrict__ Bw,
             const float* __restrict__ bias,
             void* __restrict__ Cv,
             int M, int N, int K) {
    __shared__ short sA[128 * 64];
    __shared__ short sB[NF * 32 * 64];
    const int tid = threadIdx.x;
    const int wave = tid >> 6, lane = tid & 63;
    const int g = lane >> 4, c = lane & 15;
    const int wr = wave >> 1, wc = wave & 1;
    const long m0 = (long)blockIdx.y * 128, n0 = (long)blockIdx.x * (NF * 32);

    f32x4 acc[4][NF];
    #pragma unroll
    for (int m = 0; m < 4; ++m)
        #pragma unroll
        for (int n = 0; n < NF; ++n) acc[m][n] = f32x4{0.f, 0.f, 0.f, 0.f};

    for (int k0 = 0; k0 < K; k0 += 64) {
        #pragma unroll
        for (int i = 0; i < 4; ++i) {
            int cb = (i * 4 + wave) * 64;
            int chunk = cb + lane;
            int row = chunk >> 3;
            int sc = ((chunk & 7) * 16) ^ ((row & 7) << 4);
            const char* gA = (const char*)(A + (m0 + row) * (long)K + k0) + sc;
            gload_lds16(gA, (char*)sA + cb * 16);
        }
        #pragma unroll
        for (int i = 0; i < NF; ++i) {
            int cb = (i * 4 + wave) * 64;
            int chunk = cb + lane;
            int row = chunk >> 3;
            int sc = ((chunk & 7) * 16) ^ ((row & 7) << 4);
            const char* gB = (const char*)(Bw + (n0 + row) * (long)K + k0) + sc;
            gload_lds16(gB, (char*)sB + cb * 16);
        }
        __syncthreads();
        #pragma unroll
        for (int s = 0; s < 2; ++s) {
            bf16x8 af[4], bfr[NF];
            #pragma unroll
            for (int m = 0; m < 4; ++m) {
                int row = wr * 64 + m * 16 + c;
                int kb = (s * 64 + g * 16) ^ ((row & 7) << 4);
                af[m] = *(const bf16x8*)((const char*)sA + row * 128 + kb);
            }
            #pragma unroll
            for (int n = 0; n < NF; ++n) {
                int row = wc * (NF * 16) + n * 16 + c;
                int kb = (s * 64 + g * 16) ^ ((row & 7) << 4);
                bfr[n] = *(const bf16x8*)((const char*)sB + row * 128 + kb);
            }
            #pragma unroll
            for (int m = 0; m < 4; ++m)
                #pragma unroll
                for (int n = 0; n < NF; ++n)
                    acc[m][n] = MFMA16(af[m], bfr[n], acc[m][n]);
        }
        __syncthreads();
    }

    #pragma unroll
    for (int m = 0; m < 4; ++m) {
        #pragma unroll
        for (int n = 0; n < NF; ++n) {
            long col = n0 + wc * (NF * 16) + n * 16 + c;
            float bv = bias[col];
            #pragma unroll
            for (int r = 0; r < 4; ++r) {
                long row = m0 + wr * 64 + m * 16 + g * 4 + r;
                float v = acc[m][n][r] + bv;
                if (BF16_OUT)
                    ((__hip_bfloat16*)Cv)[row * N + col] = __float2bfloat16(v);
                else
                    ((float*)Cv)[row * N + col] = v;
            }
        }
    }
}

// ---------------- attention v13: 8-wave paired blocks -----------------------
// Block = 512 threads; waves 0-3 own q-tile p (rows wave*16), waves 4-7 own
// q-tile 31-p. One shared K/V staging per block (-26% staging & barriers vs
// unpaired). Per-thread body identical to R8. 52KB LDS -> 2 blocks/CU = 16
// waves/CU (vs R8's 12). Grid 512 = exact residency; blocks balanced at 132
// active wave-iters each.

__device__ __forceinline__ void compute_tile(
    const short* sKc, const short* sVtc, short* sPw,
    bf16x8 qf0, bf16x8 qf1,
    f32x4 (&acc_o)[4], f32x4& accL, float (&m)[4],
    const float (&ab)[4][4],
    float scale, int qi0, int kv0, bool diag, int g, int c)
{
    f32x4 accs[4];
    const int swz = (c & 7) << 4;
    __builtin_amdgcn_s_setprio(1);
    #pragma unroll
    for (int nf = 0; nf < 4; ++nf) {
        const char* kb = (const char*)sKc + (nf * 16 + c) * 128;
        bf16x8 kf0 = *(const bf16x8*)(kb + ((g * 16) ^ swz));
        bf16x8 kf1 = *(const bf16x8*)(kb + ((64 + g * 16) ^ swz));
        accs[nf] = f32x4{0.f, 0.f, 0.f, 0.f};
        accs[nf] = MFMA16(qf0, kf0, accs[nf]);
        accs[nf] = MFMA16(qf1, kf1, accs[nf]);
    }
    __builtin_amdgcn_s_setprio(0);
    float s[4][4], pmax[4];
    bool ok = true;
    #pragma unroll
    for (int r = 0; r < 4; ++r) {
        int qi = qi0 + r;
        #pragma unroll
        for (int nf = 0; nf < 4; ++nf) {
            float sv = fmaf(accs[nf][r], scale, ab[nf][r]);
            if (diag && (kv0 + nf * 16 + c > qi)) sv = -1e30f;
            s[r][nf] = sv;
        }
        pmax[r] = fmaxf(fmaxf(s[r][0], s[r][1]), fmaxf(s[r][2], s[r][3]));
        ok = ok && (pmax[r] <= m[r] + 8.0f);
    }
    if (!__all(ok)) {   // rare after first tile
        #pragma unroll
        for (int r = 0; r < 4; ++r) {
            float mx = pmax[r];
            mx = fmaxf(mx, __shfl_xor(mx, 1));
            mx = fmaxf(mx, __shfl_xor(mx, 2));
            mx = fmaxf(mx, __shfl_xor(mx, 4));
            mx = fmaxf(mx, __shfl_xor(mx, 8));
            float mn = fmaxf(m[r], mx);
            float alpha = __expf(m[r] - mn);
            m[r] = mn;
            accL[r] *= alpha;
            #pragma unroll
            for (int d = 0; d < 4; ++d) acc_o[d][r] *= alpha;
        }
    }
    #pragma unroll
    for (int r = 0; r < 4; ++r)
        #pragma unroll
        for (int nf = 0; nf < 4; ++nf)
            sPw[(g * 4 + r) * 72 + nf * 16 + c] = f2bf(__expf(s[r][nf] - m[r]));
    asm volatile("s_waitcnt lgkmcnt(0)" ::: "memory");
    bf16x8 pf0 = *(const bf16x8*)((const char*)sPw + c * 144 + g * 16);
    bf16x8 pf1 = *(const bf16x8*)((const char*)sPw + c * 144 + 64 + g * 16);
    const short ONE = 0x3F80;
    const bf16x8 ones = {ONE, ONE, ONE, ONE, ONE, ONE, ONE, ONE};
    __builtin_amdgcn_s_setprio(1);
    accL = MFMA16(pf0, ones, accL);
    accL = MFMA16(pf1, ones, accL);
    #pragma unroll
    for (int d = 0; d < 4; ++d) {
        const char* vb = (const char*)sVtc + (d * 16 + c) * 144;
        bf16x8 vf0 = *(const bf16x8*)(vb + g * 16);
        bf16x8 vf1 = *(const bf16x8*)(vb + 64 + g * 16);
        acc_o[d] = MFMA16(pf0, vf0, acc_o[d]);
        acc_o[d] = MFMA16(pf1, vf1, acc_o[d]);
    }
    __builtin_amdgcn_s_setprio(0);
}

__global__ __launch_bounds__(512, 4)
void attn_kernel(const __hip_bfloat16* __restrict__ qkv,   // [B*L, 3072]
                 const float* __restrict__ alibi,          // [H, L, L]
                 const float* __restrict__ scales,         // [B]
                 __hip_bfloat16* __restrict__ out) {       // [B*L, 1024]
    __shared__ short sK[2][64 * 64];      // 16 KB, swizzled staging
    __shared__ short sVt[2][64 * 72];     // 18 KB, [64 d][64 kv + 8 pad]
    __shared__ short sP[8][16 * 72];      // 18 KB, per-wave

    const int h = blockIdx.x, b = blockIdx.y;
    const int p = blockIdx.z;             // pair id 0..15
    const int tid = threadIdx.x;
    const int wave = tid >> 6, lane = tid & 63;
    const int g = lane >> 4, c = lane & 15;
    const int tileQt = (wave < 4) ? p : (31 - p);   // own tile's q-tile index
    const int nIter = 32 - p;                       // = (31-p)+1, B-tile length
    const float scale = scales[b];
    const long base_bl = (long)b * 2048;

    const int q0 = tileQt * 64 + (wave & 3) * 16;   // own 16 q-rows

    const __hip_bfloat16* qrow = qkv + (base_bl + q0 + c) * 3072 + h * 64;
    bf16x8 qf0 = *(const bf16x8*)(qrow + g * 8);
    bf16x8 qf1 = *(const bf16x8*)(qrow + 32 + g * 8);

    const __hip_bfloat16* kg = qkv + base_bl * 3072 + 1024 + h * 64;
    const __hip_bfloat16* vg = qkv + base_bl * 3072 + 2048 + h * 64;
    const float* ab_base = alibi + (long)h * 2048 * 2048 + (long)(q0 + g * 4) * 2048;

    // V transpose staging: threads 0-255 (waves 0-3) cover 32 kv-pairs x 8 d-grps
    const int p2 = tid & 31;
    const int d0 = ((tid >> 5) & 7) * 8;
    const __hip_bfloat16* vrow = vg + (long)(2 * p2) * 3072 + d0;
    const bool vstager = (tid < 256);

    f32x4 acc[4], accL;
    float m[4];
    #pragma unroll
    for (int d = 0; d < 4; ++d) acc[d] = f32x4{0.f, 0.f, 0.f, 0.f};
    accL = f32x4{0.f, 0.f, 0.f, 0.f};
    #pragma unroll
    for (int r = 0; r < 4; ++r) m[r] = -3e38f;

    float ab[4][4], abn[4][4];

    // prologue: stage K(0) (1 chunk/thread), V(0) (waves 0-3), ab(0)
    {
        int chunk = tid;                   // 512 chunks of 16B
        int row = chunk >> 3;
        int sc = ((chunk & 7) * 16) ^ ((row & 7) << 4);
        gload_lds16((const char*)(kg + (long)row * 3072) + sc,
                    (char*)sK[0] + chunk * 16);
        if (vstager) {
            bf16x8 va = *(const bf16x8*)vrow;
            bf16x8 vb = *(const bf16x8*)(vrow + 3072);
            #pragma unroll
            for (int j = 0; j < 8; ++j) {
                unsigned pk = ((unsigned)(unsigned short)va[j]) |
                              (((unsigned)(unsigned short)vb[j]) << 16);
                *(unsigned*)((char*)sVt[0] + (d0 + j) * 144 + p2 * 4) = pk;
            }
        }
        #pragma unroll
        for (int nf = 0; nf < 4; ++nf)
            #pragma unroll
            for (int r = 0; r < 4; ++r) {
                ab[nf][r] = ab_base[(long)r * 2048 + nf * 16 + c];
                abn[nf][r] = 0.f;
            }
    }
    __syncthreads();

    for (int t = 0; t < nIter; ++t) {
        const int cur = t & 1;
        const int kv0 = t * 64;
        bf16x8 va, vb;
        const bool haveNext = (t + 1 < nIter);
        if (haveNext) {
            int chunk = tid;
            int row = chunk >> 3;
            int sc = ((chunk & 7) * 16) ^ ((row & 7) << 4);
            gload_lds16((const char*)(kg + (long)(kv0 + 64 + row) * 3072) + sc,
                        (char*)sK[cur ^ 1] + chunk * 16);
            if (vstager) {
                const __hip_bfloat16* vp = vrow + (long)(kv0 + 64) * 3072;
                va = *(const bf16x8*)vp;
                vb = *(const bf16x8*)(vp + 3072);
            }
        }
        if (t + 1 <= tileQt) {            // own-tile alibi prefetch
            #pragma unroll
            for (int nf = 0; nf < 4; ++nf)
                #pragma unroll
                for (int r = 0; r < 4; ++r)
                    abn[nf][r] = ab_base[(long)r * 2048 + kv0 + 64 + nf * 16 + c];
        }

        if (t <= tileQt)                  // wave-uniform participation
            compute_tile(sK[cur], sVt[cur], &sP[wave][0], qf0, qf1,
                         acc, accL, m, ab, scale, q0 + g * 4, kv0,
                         t == tileQt, g, c);

        if (haveNext && vstager) {
            #pragma unroll
            for (int j = 0; j < 8; ++j) {
                unsigned pk = ((unsigned)(unsigned short)va[j]) |
                              (((unsigned)(unsigned short)vb[j]) << 16);
                *(unsigned*)((char*)sVt[cur ^ 1] + (d0 + j) * 144 + p2 * 4) = pk;
            }
        }
        __syncthreads();
        #pragma unroll
        for (int nf = 0; nf < 4; ++nf)
            #pragma unroll
            for (int r = 0; r < 4; ++r)
                ab[nf][r] = abn[nf][r];
    }

    __hip_bfloat16* op = out + (base_bl + q0 + g * 4) * 1024 + h * 64;
    #pragma unroll
    for (int r = 0; r < 4; ++r) {
        float inv = 1.0f / accL[r];
        #pragma unroll
        for (int d = 0; d < 4; ++d)
            op[(long)r * 1024 + d * 16 + c] = __float2bfloat16(acc[d][r] * inv);
    }
}

extern "C" void kernel_launch(void* const* d_in, const int* in_sizes, int n_in,
                              void* d_out, int out_size, void* d_ws, size_t ws_size,
                              hipStream_t stream) {
    const float* x      = (const float*)d_in[0];
    const float* phylo  = (const float*)d_in[1];
    const float* alibi  = (const float*)d_in[2];
    const float* qkv_w  = (const float*)d_in[4];
    const float* qkv_b  = (const float*)d_in[5];
    const float* out_w  = (const float*)d_in[6];
    const float* out_b  = (const float*)d_in[7];
    const float* alphap = (const float*)d_in[8];

    char* ws = (char*)d_ws;
    __hip_bfloat16* xbf   = (__hip_bfloat16*)(ws);                 // 8 MB
    __hip_bfloat16* qwbf  = (__hip_bfloat16*)(ws + (8l << 20));    // 6 MB
    __hip_bfloat16* owbf  = (__hip_bfloat16*)(ws + (14l << 20));   // 2 MB
    __hip_bfloat16* qkvbf = (__hip_bfloat16*)(ws + (16l << 20));   // 24 MB
    __hip_bfloat16* aobf  = (__hip_bfloat16*)(ws + (40l << 20));   // 8 MB
    float* scales         = (float*)(ws + (48l << 20));            // 2 floats

    prep_kernel<<<2050, 256, 0, stream>>>(x, qkv_w, out_w, phylo, alphap,
                                          (s4v*)xbf, (s4v*)qwbf, (s4v*)owbf, scales);

    gemm_nt<1, 4><<<dim3(24, 32), 256, 0, stream>>>(xbf, qwbf, qkv_b, qkvbf,
                                                    4096, 3072, 1024);
    attn_kernel<<<dim3(16, 2, 16), 512, 0, stream>>>(qkvbf, alibi, scales, aobf);
    gemm_nt<0, 2><<<dim3(16, 32), 256, 0, stream>>>(aobf, owbf, out_b, d_out,
                                                    4096, 1024, 1024);
}

// Round 14
// 127.821 us; speedup vs baseline: 1.8283x; 1.0151x over previous
//
#include <hip/hip_runtime.h>
#include <hip/hip_bf16.h>

typedef __attribute__((ext_vector_type(8))) short bf16x8;
typedef __attribute__((ext_vector_type(4))) float f32x4;
typedef __attribute__((ext_vector_type(4))) float f4v;
typedef __attribute__((ext_vector_type(4))) short s4v;

__device__ __forceinline__ short f2bf(float f) {
    union { __hip_bfloat16 h; short s; } u;
    u.h = __float2bfloat16(f);
    return u.s;
}

__device__ __forceinline__ void gload_lds16(const void* g, void* l) {
    __builtin_amdgcn_global_load_lds(
        (const __attribute__((address_space(1))) void*)g,
        (__attribute__((address_space(3))) void*)l,
        16, 0, 0);
}

#define MFMA16(a, b, c) __builtin_amdgcn_mfma_f32_16x16x32_bf16((a), (b), (c), 0, 0, 0)

// ---------------- fused prep: 3x f32->bf16 cvt + per-batch scale ----------------
__global__ void prep_kernel(const float* __restrict__ x,
                            const float* __restrict__ qw,
                            const float* __restrict__ ow,
                            const float* __restrict__ pd,
                            const float* __restrict__ alphap,
                            s4v* __restrict__ xb, s4v* __restrict__ qb,
                            s4v* __restrict__ ob, float* __restrict__ scales) {
    __shared__ float wsum[4];
    if (blockIdx.x >= 2048) {
        int b = blockIdx.x - 2048;
        float s = 0.f;
        for (int i = threadIdx.x; i < 2048; i += 256) s += pd[b * 2048 + i];
        for (int o = 32; o; o >>= 1) s += __shfl_down(s, o);
        if ((threadIdx.x & 63) == 0) wsum[threadIdx.x >> 6] = s;
        __syncthreads();
        if (threadIdx.x == 0) {
            float t = wsum[0] + wsum[1] + wsum[2] + wsum[3];
            float mean = t * (1.0f / 2048.0f);
            float temp = fmaxf(1.0f + alphap[0] * mean, 1e-6f);
            scales[b] = 0.125f * temp;
        }
        return;
    }
    #pragma unroll
    for (int j = 0; j < 4; ++j) {
        int idx = blockIdx.x * 1024 + j * 256 + threadIdx.x;
        const f4v* src;
        s4v* dst;
        int off;
        if (idx < 1048576)      { src = (const f4v*)x;  dst = xb; off = idx; }
        else if (idx < 1835008) { src = (const f4v*)qw; dst = qb; off = idx - 1048576; }
        else                    { src = (const f4v*)ow; dst = ob; off = idx - 1835008; }
        f4v v = src[off];
        s4v o;
        #pragma unroll
        for (int k = 0; k < 4; ++k) o[k] = f2bf(v[k]);
        dst[off] = o;
    }
}

// ---------------- NT GEMM: C[M,N] = A[M,K] * B[N,K]^T + bias ----------------
// T1 XCD-aware bijective block swizzle (grid size % 8 == 0 for both uses).
template<int BF16_OUT, int NF>
__global__ __launch_bounds__(256, 2)
void gemm_nt(const __hip_bfloat16* __restrict__ A,
             const __hip_bfloat16* __restrict__ Bw,
             const float* __restrict__ bias,
             void* __restrict__ Cv,
             int M, int N, int K) {
    __shared__ short sA[128 * 64];
    __shared__ short sB[NF * 32 * 64];
    const int tid = threadIdx.x;
    const int wave = tid >> 6, lane = tid & 63;
    const int g = lane >> 4, c = lane & 15;
    const int wr = wave >> 1, wc = wave & 1;

    // XCD swizzle: contiguous tile chunk per XCD (nwg % 8 == 0)
    const int nbx = gridDim.x;
    const int nwg = nbx * gridDim.y;
    int bid = blockIdx.y * nbx + blockIdx.x;
    bid = (bid & 7) * (nwg >> 3) + (bid >> 3);
    const long m0 = (long)(bid / nbx) * 128;
    const long n0 = (long)(bid % nbx) * (NF * 32);

    f32x4 acc[4][NF];
    #pragma unroll
    for (int m = 0; m < 4; ++m)
        #pragma unroll
        for (int n = 0; n < NF; ++n) acc[m][n] = f32x4{0.f, 0.f, 0.f, 0.f};

    for (int k0 = 0; k0 < K; k0 += 64) {
        #pragma unroll
        for (int i = 0; i < 4; ++i) {
            int cb = (i * 4 + wave) * 64;
            int chunk = cb + lane;
            int row = chunk >> 3;
            int sc = ((chunk & 7) * 16) ^ ((row & 7) << 4);
            const char* gA = (const char*)(A + (m0 + row) * (long)K + k0) + sc;
            gload_lds16(gA, (char*)sA + cb * 16);
        }
        #pragma unroll
        for (int i = 0; i < NF; ++i) {
            int cb = (i * 4 + wave) * 64;
            int chunk = cb + lane;
            int row = chunk >> 3;
            int sc = ((chunk & 7) * 16) ^ ((row & 7) << 4);
            const char* gB = (const char*)(Bw + (n0 + row) * (long)K + k0) + sc;
            gload_lds16(gB, (char*)sB + cb * 16);
        }
        __syncthreads();
        #pragma unroll
        for (int s = 0; s < 2; ++s) {
            bf16x8 af[4], bfr[NF];
            #pragma unroll
            for (int m = 0; m < 4; ++m) {
                int row = wr * 64 + m * 16 + c;
                int kb = (s * 64 + g * 16) ^ ((row & 7) << 4);
                af[m] = *(const bf16x8*)((const char*)sA + row * 128 + kb);
            }
            #pragma unroll
            for (int n = 0; n < NF; ++n) {
                int row = wc * (NF * 16) + n * 16 + c;
                int kb = (s * 64 + g * 16) ^ ((row & 7) << 4);
                bfr[n] = *(const bf16x8*)((const char*)sB + row * 128 + kb);
            }
            #pragma unroll
            for (int m = 0; m < 4; ++m)
                #pragma unroll
                for (int n = 0; n < NF; ++n)
                    acc[m][n] = MFMA16(af[m], bfr[n], acc[m][n]);
        }
        __syncthreads();
    }

    #pragma unroll
    for (int m = 0; m < 4; ++m) {
        #pragma unroll
        for (int n = 0; n < NF; ++n) {
            long col = n0 + wc * (NF * 16) + n * 16 + c;
            float bv = bias[col];
            #pragma unroll
            for (int r = 0; r < 4; ++r) {
                long row = m0 + wr * 64 + m * 16 + g * 4 + r;
                float v = acc[m][n][r] + bv;
                if (BF16_OUT)
                    ((__hip_bfloat16*)Cv)[row * N + col] = __float2bfloat16(v);
                else
                    ((float*)Cv)[row * N + col] = v;
            }
        }
    }
}

// ---------------- attention (R8-exact): unpaired q-tiles, longest-first -----
// KVBLK=64 double-buffered; alibi reg-prefetch 1 iter ahead; defer-max
// softmax; ones-MFMA row-sum; async V write-late. LDS 43KB, (256,3).

__device__ __forceinline__ void compute_tile(
    const short* sKc, const short* sVtc, short* sPw,
    bf16x8 qf0, bf16x8 qf1,
    f32x4 (&acc_o)[4], f32x4& accL, float (&m)[4],
    const float (&ab)[4][4],
    float scale, int qi0, int kv0, bool diag, int g, int c)
{
    f32x4 accs[4];
    const int swz = (c & 7) << 4;
    __builtin_amdgcn_s_setprio(1);
    #pragma unroll
    for (int nf = 0; nf < 4; ++nf) {
        const char* kb = (const char*)sKc + (nf * 16 + c) * 128;
        bf16x8 kf0 = *(const bf16x8*)(kb + ((g * 16) ^ swz));
        bf16x8 kf1 = *(const bf16x8*)(kb + ((64 + g * 16) ^ swz));
        accs[nf] = f32x4{0.f, 0.f, 0.f, 0.f};
        accs[nf] = MFMA16(qf0, kf0, accs[nf]);
        accs[nf] = MFMA16(qf1, kf1, accs[nf]);
    }
    __builtin_amdgcn_s_setprio(0);
    float s[4][4], pmax[4];
    bool ok = true;
    #pragma unroll
    for (int r = 0; r < 4; ++r) {
        int qi = qi0 + r;
        #pragma unroll
        for (int nf = 0; nf < 4; ++nf) {
            float sv = fmaf(accs[nf][r], scale, ab[nf][r]);
            if (diag && (kv0 + nf * 16 + c > qi)) sv = -1e30f;
            s[r][nf] = sv;
        }
        pmax[r] = fmaxf(fmaxf(s[r][0], s[r][1]), fmaxf(s[r][2], s[r][3]));
        ok = ok && (pmax[r] <= m[r] + 8.0f);
    }
    if (!__all(ok)) {   // rare after first tile
        #pragma unroll
        for (int r = 0; r < 4; ++r) {
            float mx = pmax[r];
            mx = fmaxf(mx, __shfl_xor(mx, 1));
            mx = fmaxf(mx, __shfl_xor(mx, 2));
            mx = fmaxf(mx, __shfl_xor(mx, 4));
            mx = fmaxf(mx, __shfl_xor(mx, 8));
            float mn = fmaxf(m[r], mx);
            float alpha = __expf(m[r] - mn);
            m[r] = mn;
            accL[r] *= alpha;
            #pragma unroll
            for (int d = 0; d < 4; ++d) acc_o[d][r] *= alpha;
        }
    }
    #pragma unroll
    for (int r = 0; r < 4; ++r)
        #pragma unroll
        for (int nf = 0; nf < 4; ++nf)
            sPw[(g * 4 + r) * 72 + nf * 16 + c] = f2bf(__expf(s[r][nf] - m[r]));
    asm volatile("s_waitcnt lgkmcnt(0)" ::: "memory");
    bf16x8 pf0 = *(const bf16x8*)((const char*)sPw + c * 144 + g * 16);
    bf16x8 pf1 = *(const bf16x8*)((const char*)sPw + c * 144 + 64 + g * 16);
    const short ONE = 0x3F80;
    const bf16x8 ones = {ONE, ONE, ONE, ONE, ONE, ONE, ONE, ONE};
    __builtin_amdgcn_s_setprio(1);
    accL = MFMA16(pf0, ones, accL);
    accL = MFMA16(pf1, ones, accL);
    #pragma unroll
    for (int d = 0; d < 4; ++d) {
        const char* vb = (const char*)sVtc + (d * 16 + c) * 144;
        bf16x8 vf0 = *(const bf16x8*)(vb + g * 16);
        bf16x8 vf1 = *(const bf16x8*)(vb + 64 + g * 16);
        acc_o[d] = MFMA16(pf0, vf0, acc_o[d]);
        acc_o[d] = MFMA16(pf1, vf1, acc_o[d]);
    }
    __builtin_amdgcn_s_setprio(0);
}

__global__ __launch_bounds__(256, 3)
void attn_kernel(const __hip_bfloat16* __restrict__ qkv,   // [B*L, 3072]
                 const float* __restrict__ alibi,          // [H, L, L]
                 const float* __restrict__ scales,         // [B]
                 __hip_bfloat16* __restrict__ out) {       // [B*L, 1024]
    __shared__ short sK[2][64 * 64];      // 16 KB, swizzled staging
    __shared__ short sVt[2][64 * 72];     // 18 KB, [64 d][64 kv + 8 pad]
    __shared__ short sP[4][16 * 72];      // 9 KB, per-wave

    const int h = blockIdx.x, b = blockIdx.y;
    const int qt = 31 - blockIdx.z;       // longest q-tiles dispatched first
    const int nIter = qt + 1;
    const int tid = threadIdx.x;
    const int wave = tid >> 6, lane = tid & 63;
    const int g = lane >> 4, c = lane & 15;
    const float scale = scales[b];
    const long base_bl = (long)b * 2048;

    const int q0 = qt * 64 + wave * 16;

    const __hip_bfloat16* qrow = qkv + (base_bl + q0 + c) * 3072 + h * 64;
    bf16x8 qf0 = *(const bf16x8*)(qrow + g * 8);
    bf16x8 qf1 = *(const bf16x8*)(qrow + 32 + g * 8);

    const __hip_bfloat16* kg = qkv + base_bl * 3072 + 1024 + h * 64;
    const __hip_bfloat16* vg = qkv + base_bl * 3072 + 2048 + h * 64;
    const float* ab_base = alibi + (long)h * 2048 * 2048 + (long)(q0 + g * 4) * 2048;

    const int p2 = tid & 31;
    const int d0 = (tid >> 5) * 8;
    const __hip_bfloat16* vrow = vg + (long)(2 * p2) * 3072 + d0;

    f32x4 acc[4], accL;
    float m[4];
    #pragma unroll
    for (int d = 0; d < 4; ++d) acc[d] = f32x4{0.f, 0.f, 0.f, 0.f};
    accL = f32x4{0.f, 0.f, 0.f, 0.f};
    #pragma unroll
    for (int r = 0; r < 4; ++r) m[r] = -3e38f;

    float ab[4][4], abn[4][4];

    // prologue: stage K(0), V(0), ab(0)
    {
        #pragma unroll
        for (int i = 0; i < 2; ++i) {
            int cb = (i * 4 + wave) * 64;
            int chunk = cb + lane;
            int row = chunk >> 3;
            int sc = ((chunk & 7) * 16) ^ ((row & 7) << 4);
            gload_lds16((const char*)(kg + (long)row * 3072) + sc,
                        (char*)sK[0] + cb * 16);
        }
        bf16x8 va = *(const bf16x8*)vrow;
        bf16x8 vb = *(const bf16x8*)(vrow + 3072);
        #pragma unroll
        for (int j = 0; j < 8; ++j) {
            unsigned pk = ((unsigned)(unsigned short)va[j]) |
                          (((unsigned)(unsigned short)vb[j]) << 16);
            *(unsigned*)((char*)sVt[0] + (d0 + j) * 144 + p2 * 4) = pk;
        }
        #pragma unroll
        for (int nf = 0; nf < 4; ++nf)
            #pragma unroll
            for (int r = 0; r < 4; ++r) {
                ab[nf][r] = ab_base[(long)r * 2048 + nf * 16 + c];
                abn[nf][r] = 0.f;
            }
    }
    __syncthreads();

    for (int t = 0; t < nIter; ++t) {
        const int cur = t & 1;
        const int kv0 = t * 64;
        bf16x8 va, vb;
        const bool haveNext = (t + 1 < nIter);
        if (haveNext) {
            // issue next K tile (direct to LDS) + next V loads (regs, write late)
            #pragma unroll
            for (int i = 0; i < 2; ++i) {
                int cb = (i * 4 + wave) * 64;
                int chunk = cb + lane;
                int row = chunk >> 3;
                int sc = ((chunk & 7) * 16) ^ ((row & 7) << 4);
                gload_lds16((const char*)(kg + (long)(kv0 + 64 + row) * 3072) + sc,
                            (char*)sK[cur ^ 1] + cb * 16);
            }
            const __hip_bfloat16* vp = vrow + (long)(kv0 + 64) * 3072;
            va = *(const bf16x8*)vp;
            vb = *(const bf16x8*)(vp + 3072);
            #pragma unroll
            for (int nf = 0; nf < 4; ++nf)
                #pragma unroll
                for (int r = 0; r < 4; ++r)
                    abn[nf][r] = ab_base[(long)r * 2048 + kv0 + 64 + nf * 16 + c];
        }

        compute_tile(sK[cur], sVt[cur], &sP[wave][0], qf0, qf1,
                     acc, accL, m, ab, scale, q0 + g * 4, kv0, t == qt, g, c);

        if (haveNext) {
            #pragma unroll
            for (int j = 0; j < 8; ++j) {
                unsigned pk = ((unsigned)(unsigned short)va[j]) |
                              (((unsigned)(unsigned short)vb[j]) << 16);
                *(unsigned*)((char*)sVt[cur ^ 1] + (d0 + j) * 144 + p2 * 4) = pk;
            }
        }
        __syncthreads();
        #pragma unroll
        for (int nf = 0; nf < 4; ++nf)
            #pragma unroll
            for (int r = 0; r < 4; ++r)
                ab[nf][r] = abn[nf][r];
    }

    __hip_bfloat16* op = out + (base_bl + q0 + g * 4) * 1024 + h * 64;
    #pragma unroll
    for (int r = 0; r < 4; ++r) {
        float inv = 1.0f / accL[r];
        #pragma unroll
        for (int d = 0; d < 4; ++d)
            op[(long)r * 1024 + d * 16 + c] = __float2bfloat16(acc[d][r] * inv);
    }
}

extern "C" void kernel_launch(void* const* d_in, const int* in_sizes, int n_in,
                              void* d_out, int out_size, void* d_ws, size_t ws_size,
                              hipStream_t stream) {
    const float* x      = (const float*)d_in[0];
    const float* phylo  = (const float*)d_in[1];
    const float* alibi  = (const float*)d_in[2];
    const float* qkv_w  = (const float*)d_in[4];
    const float* qkv_b  = (const float*)d_in[5];
    const float* out_w  = (const float*)d_in[6];
    const float* out_b  = (const float*)d_in[7];
    const float* alphap = (const float*)d_in[8];

    char* ws = (char*)d_ws;
    __hip_bfloat16* xbf   = (__hip_bfloat16*)(ws);                 // 8 MB
    __hip_bfloat16* qwbf  = (__hip_bfloat16*)(ws + (8l << 20));    // 6 MB
    __hip_bfloat16* owbf  = (__hip_bfloat16*)(ws + (14l << 20));   // 2 MB
    __hip_bfloat16* qkvbf = (__hip_bfloat16*)(ws + (16l << 20));   // 24 MB
    __hip_bfloat16* aobf  = (__hip_bfloat16*)(ws + (40l << 20));   // 8 MB
    float* scales         = (float*)(ws + (48l << 20));            // 2 floats

    prep_kernel<<<2050, 256, 0, stream>>>(x, qkv_w, out_w, phylo, alphap,
                                          (s4v*)xbf, (s4v*)qwbf, (s4v*)owbf, scales);

    gemm_nt<1, 4><<<dim3(24, 32), 256, 0, stream>>>(xbf, qwbf, qkv_b, qkvbf,
                                                    4096, 3072, 1024);
    attn_kernel<<<dim3(16, 2, 32), 256, 0, stream>>>(qkvbf, alibi, scales, aobf);
    gemm_nt<0, 2><<<dim3(16, 32), 256, 0, stream>>>(aobf, owbf, out_b, d_out,
                                                    4096, 1024, 1024);
}

// Round 15
// 126.153 us; speedup vs baseline: 1.8525x; 1.0132x over previous
//
#include <hip/hip_runtime.h>
#include <hip/hip_bf16.h>

typedef __attribute__((ext_vector_type(8))) short bf16x8;
typedef __attribute__((ext_vector_type(4))) float f32x4;
typedef __attribute__((ext_vector_type(4))) float f4v;
typedef __attribute__((ext_vector_type(4))) short s4v;

__device__ __forceinline__ short f2bf(float f) {
    union { __hip_bfloat16 h; short s; } u;
    u.h = __float2bfloat16(f);
    return u.s;
}

__device__ __forceinline__ void gload_lds16(const void* g, void* l) {
    __builtin_amdgcn_global_load_lds(
        (const __attribute__((address_space(1))) void*)g,
        (__attribute__((address_space(3))) void*)l,
        16, 0, 0);
}

#define MFMA16(a, b, c) __builtin_amdgcn_mfma_f32_16x16x32_bf16((a), (b), (c), 0, 0, 0)

// ---------------- fused prep: 3x f32->bf16 cvt + per-batch scale ----------------
__global__ void prep_kernel(const float* __restrict__ x,
                            const float* __restrict__ qw,
                            const float* __restrict__ ow,
                            const float* __restrict__ pd,
                            const float* __restrict__ alphap,
                            s4v* __restrict__ xb, s4v* __restrict__ qb,
                            s4v* __restrict__ ob, float* __restrict__ scales) {
    __shared__ float wsum[4];
    if (blockIdx.x >= 2048) {
        int b = blockIdx.x - 2048;
        float s = 0.f;
        for (int i = threadIdx.x; i < 2048; i += 256) s += pd[b * 2048 + i];
        for (int o = 32; o; o >>= 1) s += __shfl_down(s, o);
        if ((threadIdx.x & 63) == 0) wsum[threadIdx.x >> 6] = s;
        __syncthreads();
        if (threadIdx.x == 0) {
            float t = wsum[0] + wsum[1] + wsum[2] + wsum[3];
            float mean = t * (1.0f / 2048.0f);
            float temp = fmaxf(1.0f + alphap[0] * mean, 1e-6f);
            scales[b] = 0.125f * temp;
        }
        return;
    }
    #pragma unroll
    for (int j = 0; j < 4; ++j) {
        int idx = blockIdx.x * 1024 + j * 256 + threadIdx.x;
        const f4v* src;
        s4v* dst;
        int off;
        if (idx < 1048576)      { src = (const f4v*)x;  dst = xb; off = idx; }
        else if (idx < 1835008) { src = (const f4v*)qw; dst = qb; off = idx - 1048576; }
        else                    { src = (const f4v*)ow; dst = ob; off = idx - 1835008; }
        f4v v = src[off];
        s4v o;
        #pragma unroll
        for (int k = 0; k < 4; ++k) o[k] = f2bf(v[k]);
        dst[off] = o;
    }
}

// ---------------- NT GEMM: C[M,N] = A[M,K] * B[N,K]^T + bias ----------------
// T1 XCD-aware bijective block swizzle (grid size % 8 == 0 for both uses).
template<int BF16_OUT, int NF>
__global__ __launch_bounds__(256, 2)
void gemm_nt(const __hip_bfloat16* __restrict__ A,
             const __hip_bfloat16* __restrict__ Bw,
             const float* __restrict__ bias,
             void* __restrict__ Cv,
             int M, int N, int K) {
    __shared__ short sA[128 * 64];
    __shared__ short sB[NF * 32 * 64];
    const int tid = threadIdx.x;
    const int wave = tid >> 6, lane = tid & 63;
    const int g = lane >> 4, c = lane & 15;
    const int wr = wave >> 1, wc = wave & 1;

    // XCD swizzle: contiguous tile chunk per XCD (nwg % 8 == 0)
    const int nbx = gridDim.x;
    const int nwg = nbx * gridDim.y;
    int bid = blockIdx.y * nbx + blockIdx.x;
    bid = (bid & 7) * (nwg >> 3) + (bid >> 3);
    const long m0 = (long)(bid / nbx) * 128;
    const long n0 = (long)(bid % nbx) * (NF * 32);

    f32x4 acc[4][NF];
    #pragma unroll
    for (int m = 0; m < 4; ++m)
        #pragma unroll
        for (int n = 0; n < NF; ++n) acc[m][n] = f32x4{0.f, 0.f, 0.f, 0.f};

    for (int k0 = 0; k0 < K; k0 += 64) {
        #pragma unroll
        for (int i = 0; i < 4; ++i) {
            int cb = (i * 4 + wave) * 64;
            int chunk = cb + lane;
            int row = chunk >> 3;
            int sc = ((chunk & 7) * 16) ^ ((row & 7) << 4);
            const char* gA = (const char*)(A + (m0 + row) * (long)K + k0) + sc;
            gload_lds16(gA, (char*)sA + cb * 16);
        }
        #pragma unroll
        for (int i = 0; i < NF; ++i) {
            int cb = (i * 4 + wave) * 64;
            int chunk = cb + lane;
            int row = chunk >> 3;
            int sc = ((chunk & 7) * 16) ^ ((row & 7) << 4);
            const char* gB = (const char*)(Bw + (n0 + row) * (long)K + k0) + sc;
            gload_lds16(gB, (char*)sB + cb * 16);
        }
        __syncthreads();
        #pragma unroll
        for (int s = 0; s < 2; ++s) {
            bf16x8 af[4], bfr[NF];
            #pragma unroll
            for (int m = 0; m < 4; ++m) {
                int row = wr * 64 + m * 16 + c;
                int kb = (s * 64 + g * 16) ^ ((row & 7) << 4);
                af[m] = *(const bf16x8*)((const char*)sA + row * 128 + kb);
            }
            #pragma unroll
            for (int n = 0; n < NF; ++n) {
                int row = wc * (NF * 16) + n * 16 + c;
                int kb = (s * 64 + g * 16) ^ ((row & 7) << 4);
                bfr[n] = *(const bf16x8*)((const char*)sB + row * 128 + kb);
            }
            #pragma unroll
            for (int m = 0; m < 4; ++m)
                #pragma unroll
                for (int n = 0; n < NF; ++n)
                    acc[m][n] = MFMA16(af[m], bfr[n], acc[m][n]);
        }
        __syncthreads();
    }

    #pragma unroll
    for (int m = 0; m < 4; ++m) {
        #pragma unroll
        for (int n = 0; n < NF; ++n) {
            long col = n0 + wc * (NF * 16) + n * 16 + c;
            float bv = bias[col];
            #pragma unroll
            for (int r = 0; r < 4; ++r) {
                long row = m0 + wr * 64 + m * 16 + g * 4 + r;
                float v = acc[m][n][r] + bv;
                if (BF16_OUT)
                    ((__hip_bfloat16*)Cv)[row * N + col] = __float2bfloat16(v);
                else
                    ((float*)Cv)[row * N + col] = v;
            }
        }
    }
}

// ---------------- attention v15: R8 body, sP aliased onto sVt[cur^1] --------
// sP's live range is inside compute_tile only; sVt[cur^1] is idle there (its
// V-late-write happens after). Wave w's P rows [16w,16w+16) == the V rows
// wave w itself writes late -> no cross-wave hazard; per-wave in-order DS
// sequences P-reads before V-writes. LDS 43 -> 34 KB => 4 blocks/CU.

__device__ __forceinline__ void compute_tile(
    const short* sKc, const short* sVtc, short* sPw,
    bf16x8 qf0, bf16x8 qf1,
    f32x4 (&acc_o)[4], f32x4& accL, float (&m)[4],
    const float (&ab)[4][4],
    float scale, int qi0, int kv0, bool diag, int g, int c)
{
    f32x4 accs[4];
    const int swz = (c & 7) << 4;
    __builtin_amdgcn_s_setprio(1);
    #pragma unroll
    for (int nf = 0; nf < 4; ++nf) {
        const char* kb = (const char*)sKc + (nf * 16 + c) * 128;
        bf16x8 kf0 = *(const bf16x8*)(kb + ((g * 16) ^ swz));
        bf16x8 kf1 = *(const bf16x8*)(kb + ((64 + g * 16) ^ swz));
        accs[nf] = f32x4{0.f, 0.f, 0.f, 0.f};
        accs[nf] = MFMA16(qf0, kf0, accs[nf]);
        accs[nf] = MFMA16(qf1, kf1, accs[nf]);
    }
    __builtin_amdgcn_s_setprio(0);
    float s[4][4], pmax[4];
    bool ok = true;
    #pragma unroll
    for (int r = 0; r < 4; ++r) {
        int qi = qi0 + r;
        #pragma unroll
        for (int nf = 0; nf < 4; ++nf) {
            float sv = fmaf(accs[nf][r], scale, ab[nf][r]);
            if (diag && (kv0 + nf * 16 + c > qi)) sv = -1e30f;
            s[r][nf] = sv;
        }
        pmax[r] = fmaxf(fmaxf(s[r][0], s[r][1]), fmaxf(s[r][2], s[r][3]));
        ok = ok && (pmax[r] <= m[r] + 8.0f);
    }
    if (!__all(ok)) {   // rare after first tile
        #pragma unroll
        for (int r = 0; r < 4; ++r) {
            float mx = pmax[r];
            mx = fmaxf(mx, __shfl_xor(mx, 1));
            mx = fmaxf(mx, __shfl_xor(mx, 2));
            mx = fmaxf(mx, __shfl_xor(mx, 4));
            mx = fmaxf(mx, __shfl_xor(mx, 8));
            float mn = fmaxf(m[r], mx);
            float alpha = __expf(m[r] - mn);
            m[r] = mn;
            accL[r] *= alpha;
            #pragma unroll
            for (int d = 0; d < 4; ++d) acc_o[d][r] *= alpha;
        }
    }
    #pragma unroll
    for (int r = 0; r < 4; ++r)
        #pragma unroll
        for (int nf = 0; nf < 4; ++nf)
            sPw[(g * 4 + r) * 72 + nf * 16 + c] = f2bf(__expf(s[r][nf] - m[r]));
    asm volatile("s_waitcnt lgkmcnt(0)" ::: "memory");
    bf16x8 pf0 = *(const bf16x8*)((const char*)sPw + c * 144 + g * 16);
    bf16x8 pf1 = *(const bf16x8*)((const char*)sPw + c * 144 + 64 + g * 16);
    const short ONE = 0x3F80;
    const bf16x8 ones = {ONE, ONE, ONE, ONE, ONE, ONE, ONE, ONE};
    __builtin_amdgcn_s_setprio(1);
    accL = MFMA16(pf0, ones, accL);
    accL = MFMA16(pf1, ones, accL);
    #pragma unroll
    for (int d = 0; d < 4; ++d) {
        const char* vb = (const char*)sVtc + (d * 16 + c) * 144;
        bf16x8 vf0 = *(const bf16x8*)(vb + g * 16);
        bf16x8 vf1 = *(const bf16x8*)(vb + 64 + g * 16);
        acc_o[d] = MFMA16(pf0, vf0, acc_o[d]);
        acc_o[d] = MFMA16(pf1, vf1, acc_o[d]);
    }
    __builtin_amdgcn_s_setprio(0);
}

__global__ __launch_bounds__(256, 4)
void attn_kernel(const __hip_bfloat16* __restrict__ qkv,   // [B*L, 3072]
                 const float* __restrict__ alibi,          // [H, L, L]
                 const float* __restrict__ scales,         // [B]
                 __hip_bfloat16* __restrict__ out) {       // [B*L, 1024]
    __shared__ short sK[2][64 * 64];      // 16 KB, swizzled staging
    __shared__ short sVt[2][64 * 72];     // 18 KB, [64 d][64 kv + 8 pad]
    // sP eliminated: wave w uses rows [16w,16w+16) of sVt[cur^1] as P scratch.

    const int h = blockIdx.x, b = blockIdx.y;
    const int qt = 31 - blockIdx.z;       // longest q-tiles dispatched first
    const int nIter = qt + 1;
    const int tid = threadIdx.x;
    const int wave = tid >> 6, lane = tid & 63;
    const int g = lane >> 4, c = lane & 15;
    const float scale = scales[b];
    const long base_bl = (long)b * 2048;

    const int q0 = qt * 64 + wave * 16;

    const __hip_bfloat16* qrow = qkv + (base_bl + q0 + c) * 3072 + h * 64;
    bf16x8 qf0 = *(const bf16x8*)(qrow + g * 8);
    bf16x8 qf1 = *(const bf16x8*)(qrow + 32 + g * 8);

    const __hip_bfloat16* kg = qkv + base_bl * 3072 + 1024 + h * 64;
    const __hip_bfloat16* vg = qkv + base_bl * 3072 + 2048 + h * 64;
    const float* ab_base = alibi + (long)h * 2048 * 2048 + (long)(q0 + g * 4) * 2048;

    const int p2 = tid & 31;
    const int d0 = (tid >> 5) * 8;
    const __hip_bfloat16* vrow = vg + (long)(2 * p2) * 3072 + d0;

    f32x4 acc[4], accL;
    float m[4];
    #pragma unroll
    for (int d = 0; d < 4; ++d) acc[d] = f32x4{0.f, 0.f, 0.f, 0.f};
    accL = f32x4{0.f, 0.f, 0.f, 0.f};
    #pragma unroll
    for (int r = 0; r < 4; ++r) m[r] = -3e38f;

    float ab[4][4], abn[4][4];

    // prologue: stage K(0), V(0), ab(0)
    {
        #pragma unroll
        for (int i = 0; i < 2; ++i) {
            int cb = (i * 4 + wave) * 64;
            int chunk = cb + lane;
            int row = chunk >> 3;
            int sc = ((chunk & 7) * 16) ^ ((row & 7) << 4);
            gload_lds16((const char*)(kg + (long)row * 3072) + sc,
                        (char*)sK[0] + cb * 16);
        }
        bf16x8 va = *(const bf16x8*)vrow;
        bf16x8 vb = *(const bf16x8*)(vrow + 3072);
        #pragma unroll
        for (int j = 0; j < 8; ++j) {
            unsigned pk = ((unsigned)(unsigned short)va[j]) |
                          (((unsigned)(unsigned short)vb[j]) << 16);
            *(unsigned*)((char*)sVt[0] + (d0 + j) * 144 + p2 * 4) = pk;
        }
        #pragma unroll
        for (int nf = 0; nf < 4; ++nf)
            #pragma unroll
            for (int r = 0; r < 4; ++r) {
                ab[nf][r] = ab_base[(long)r * 2048 + nf * 16 + c];
                abn[nf][r] = 0.f;
            }
    }
    __syncthreads();

    for (int t = 0; t < nIter; ++t) {
        const int cur = t & 1;
        const int kv0 = t * 64;
        bf16x8 va, vb;
        const bool haveNext = (t + 1 < nIter);
        if (haveNext) {
            // issue next K tile (direct to LDS) + next V loads (regs, write late)
            #pragma unroll
            for (int i = 0; i < 2; ++i) {
                int cb = (i * 4 + wave) * 64;
                int chunk = cb + lane;
                int row = chunk >> 3;
                int sc = ((chunk & 7) * 16) ^ ((row & 7) << 4);
                gload_lds16((const char*)(kg + (long)(kv0 + 64 + row) * 3072) + sc,
                            (char*)sK[cur ^ 1] + cb * 16);
            }
            const __hip_bfloat16* vp = vrow + (long)(kv0 + 64) * 3072;
            va = *(const bf16x8*)vp;
            vb = *(const bf16x8*)(vp + 3072);
            #pragma unroll
            for (int nf = 0; nf < 4; ++nf)
                #pragma unroll
                for (int r = 0; r < 4; ++r)
                    abn[nf][r] = ab_base[(long)r * 2048 + kv0 + 64 + nf * 16 + c];
        }

        // P scratch = this wave's 16 rows of the idle V buffer (stride 72)
        short* sPw = &sVt[cur ^ 1][0] + wave * (16 * 72);
        compute_tile(sK[cur], sVt[cur], sPw, qf0, qf1,
                     acc, accL, m, ab, scale, q0 + g * 4, kv0, t == qt, g, c);

        if (haveNext) {
            // V-late-write: wave w writes rows [16w,16w+16) — same region as
            // its own P scratch; per-wave in-order DS makes this safe.
            #pragma unroll
            for (int j = 0; j < 8; ++j) {
                unsigned pk = ((unsigned)(unsigned short)va[j]) |
                              (((unsigned)(unsigned short)vb[j]) << 16);
                *(unsigned*)((char*)sVt[cur ^ 1] + (d0 + j) * 144 + p2 * 4) = pk;
            }
        }
        __syncthreads();
        #pragma unroll
        for (int nf = 0; nf < 4; ++nf)
            #pragma unroll
            for (int r = 0; r < 4; ++r)
                ab[nf][r] = abn[nf][r];
    }

    __hip_bfloat16* op = out + (base_bl + q0 + g * 4) * 1024 + h * 64;
    #pragma unroll
    for (int r = 0; r < 4; ++r) {
        float inv = 1.0f / accL[r];
        #pragma unroll
        for (int d = 0; d < 4; ++d)
            op[(long)r * 1024 + d * 16 + c] = __float2bfloat16(acc[d][r] * inv);
    }
}

extern "C" void kernel_launch(void* const* d_in, const int* in_sizes, int n_in,
                              void* d_out, int out_size, void* d_ws, size_t ws_size,
                              hipStream_t stream) {
    const float* x      = (const float*)d_in[0];
    const float* phylo  = (const float*)d_in[1];
    const float* alibi  = (const float*)d_in[2];
    const float* qkv_w  = (const float*)d_in[4];
    const float* qkv_b  = (const float*)d_in[5];
    const float* out_w  = (const float*)d_in[6];
    const float* out_b  = (const float*)d_in[7];
    const float* alphap = (const float*)d_in[8];

    char* ws = (char*)d_ws;
    __hip_bfloat16* xbf   = (__hip_bfloat16*)(ws);                 // 8 MB
    __hip_bfloat16* qwbf  = (__hip_bfloat16*)(ws + (8l << 20));    // 6 MB
    __hip_bfloat16* owbf  = (__hip_bfloat16*)(ws + (14l << 20));   // 2 MB
    __hip_bfloat16* qkvbf = (__hip_bfloat16*)(ws + (16l << 20));   // 24 MB
    __hip_bfloat16* aobf  = (__hip_bfloat16*)(ws + (40l << 20));   // 8 MB
    float* scales         = (float*)(ws + (48l << 20));            // 2 floats

    prep_kernel<<<2050, 256, 0, stream>>>(x, qkv_w, out_w, phylo, alphap,
                                          (s4v*)xbf, (s4v*)qwbf, (s4v*)owbf, scales);

    gemm_nt<1, 4><<<dim3(24, 32), 256, 0, stream>>>(xbf, qwbf, qkv_b, qkvbf,
                                                    4096, 3072, 1024);
    attn_kernel<<<dim3(16, 2, 32), 256, 0, stream>>>(qkvbf, alibi, scales, aobf);
    gemm_nt<0, 2><<<dim3(16, 32), 256, 0, stream>>>(aobf, owbf, out_b, d_out,
                                                    4096, 1024, 1024);
}